// Round 9
// baseline (10390.958 us; speedup 1.0000x reference)
//
#include <hip/hip_runtime.h>

// approxmatch EMD (Fan et al.) on MI355X, B=4, N=M=4096, layout (B,3,N).
// Round 9: mega-kernel (software grid barrier, R8-proven protocol) at FULL
// occupancy. R8 post-mortem: 512 blocks = 8 waves/CU -> VALUBusy 14% (latency-
// bound per wave; throughput ~ resident waves). Here: 2048 blocks x 256 thr =
// 8 blocks/CU = 32 waves/CU (hw max). Co-residency: TILE 512 -> LDS 10.3 KB
// (15/CU capacity), launch_bounds(256,8) -> VGPR cap 64 (RPW=2 fits), wave
// slots 8x4=32 exactly. Math identical to validated R6 kernels: packed v2f,
// exp-chaining e_t = (e_{t+1})^4, pass3(t)+pass1(t+1) fused, level-0 special.

#define NPTS 4096
#define BATCH 4
#define EMD_EPS 1e-9f
#define TILE 512         // columns staged per LDS stage (10.3 KB total smem)
#define RPW 2            // rows per wave, in registers
#define THREADS 256      // 4 waves
#define RPB 8            // rows per block = 4 waves * RPW
#define GRID_BLKS 2048   // 512 blocks per batch; 8 blocks/CU

typedef float v2f __attribute__((ext_vector_type(2)));

__device__ __forceinline__ float fexp2(float x) {
#if __has_builtin(__builtin_amdgcn_exp2f)
    return __builtin_amdgcn_exp2f(x);
#else
    return exp2f(x);
#endif
}
__device__ __forceinline__ float fsqrt(float x) {
#if __has_builtin(__builtin_amdgcn_sqrtf)
    return __builtin_amdgcn_sqrtf(x);
#else
    return __sqrtf(x);
#endif
}

__device__ __forceinline__ float wave_reduce(float v) {
    v += __shfl_xor(v, 32);
    v += __shfl_xor(v, 16);
    v += __shfl_xor(v, 8);
    v += __shfl_xor(v, 4);
    v += __shfl_xor(v, 2);
    v += __shfl_xor(v, 1);
    return v;
}

// ---------------------------------------------------------------- software grid barrier
// Slot k: cnt at u[k*32], flag at u[k*32+16] (separate 64B lines). Zeroed by
// hipMemsetAsync before launch (d_ws is re-poisoned every replay).
__device__ __forceinline__ void grid_barrier(unsigned* bar, int k) {
    __syncthreads();
    if (threadIdx.x == 0) {
        __threadfence();
        unsigned* cnt = bar + k * 32;
        unsigned* flg = bar + k * 32 + 16;
        unsigned old = __hip_atomic_fetch_add(cnt, 1u, __ATOMIC_ACQ_REL,
                                              __HIP_MEMORY_SCOPE_AGENT);
        if (old == GRID_BLKS - 1) {
            __hip_atomic_store(flg, 1u, __ATOMIC_RELEASE, __HIP_MEMORY_SCOPE_AGENT);
        } else {
            while (__hip_atomic_load(flg, __ATOMIC_ACQUIRE,
                                     __HIP_MEMORY_SCOPE_AGENT) == 0u)
                __builtin_amdgcn_s_sleep(1);
        }
        __threadfence();
    }
    __syncthreads();
}

// ---------------------------------------------------------------- phase: row pass, sweep 0
// remainR == 1 -> ratioL = 1/(eps + sum exp2(ls2*d)); inits remainL/remainR.
__device__ __forceinline__ void phase_rowL0(
        const float* __restrict__ x1, const float* __restrict__ x2,
        float* __restrict__ rl_b, float* __restrict__ mL_b, float* __restrict__ mR_b,
        float4* sA, float2* sZ, int row0, int lane, int tid, float ls2) {
    const float2* x2x = (const float2*)(x2);
    const float2* x2y = (const float2*)(x2 + NPTS);
    const float2* x2z = (const float2*)(x2 + 2 * NPTS);
    float px[RPW], py[RPW], pz[RPW];
    v2f acc[RPW];
#pragma unroll
    for (int r = 0; r < RPW; ++r) {
        px[r] = x1[row0 + r];
        py[r] = x1[NPTS + row0 + r];
        pz[r] = x1[2 * NPTS + row0 + r];
        acc[r] = (v2f)(0.0f);
    }
    for (int c0 = 0; c0 < NPTS; c0 += TILE) {
        __syncthreads();
        {
            int e = c0 / 2 + tid;                 // TILE/2 == THREADS
            float2 xx = x2x[e], yy = x2y[e];
            sA[tid] = make_float4(xx.x, xx.y, yy.x, yy.y);
            sZ[tid] = x2z[e];
        }
        __syncthreads();
#pragma unroll 2
        for (int j = 0; j < TILE / 128; ++j) {
            float4 a = sA[lane + 64 * j];
            float2 z = sZ[lane + 64 * j];
            v2f ax = {a.x, a.y}, ay = {a.z, a.w}, az = {z.x, z.y};
#pragma unroll
            for (int r = 0; r < RPW; ++r) {
                v2f dx = px[r] - ax, dy = py[r] - ay, dz = pz[r] - az;
                v2f d = dx * dx + dy * dy + dz * dz;
                v2f sd = ls2 * d;
                v2f e2 = {fexp2(sd.x), fexp2(sd.y)};
                acc[r] += e2;
            }
        }
    }
#pragma unroll
    for (int r = 0; r < RPW; ++r) {
        float s = wave_reduce(acc[r].x + acc[r].y);
        if (lane == 0) {
            rl_b[row0 + r] = 1.0f / (EMD_EPS + s);
            mL_b[row0 + r] = 1.0f;
            mR_b[row0 + r] = 1.0f;
        }
    }
}

// ---------------------------------------------------------------- phase: col pass
__device__ __forceinline__ void phase_col(
        const float* __restrict__ x1, const float* __restrict__ x2,
        const float* __restrict__ rl_b, float* __restrict__ rr_b,
        float* __restrict__ mR_b,
        float4* sA, float4* sB, int col0, int lane, int tid, float ls2) {
    const float2* x1x = (const float2*)(x1);
    const float2* x1y = (const float2*)(x1 + NPTS);
    const float2* x1z = (const float2*)(x1 + 2 * NPTS);
    const float2* wLv = (const float2*)(rl_b);
    float px[RPW], py[RPW], pz[RPW];
    v2f acc[RPW];
#pragma unroll
    for (int r = 0; r < RPW; ++r) {
        px[r] = x2[col0 + r];
        py[r] = x2[NPTS + col0 + r];
        pz[r] = x2[2 * NPTS + col0 + r];
        acc[r] = (v2f)(0.0f);
    }
    for (int c0 = 0; c0 < NPTS; c0 += TILE) {
        __syncthreads();
        {
            int e = c0 / 2 + tid;
            float2 xx = x1x[e], yy = x1y[e], zz = x1z[e], ww = wLv[e];
            sA[tid] = make_float4(xx.x, xx.y, yy.x, yy.y);
            sB[tid] = make_float4(zz.x, zz.y, ww.x, ww.y);
        }
        __syncthreads();
#pragma unroll 2
        for (int j = 0; j < TILE / 128; ++j) {
            float4 a = sA[lane + 64 * j];
            float4 bq = sB[lane + 64 * j];
            v2f ax = {a.x, a.y}, ay = {a.z, a.w};
            v2f az = {bq.x, bq.y}, aw = {bq.z, bq.w};
#pragma unroll
            for (int r = 0; r < RPW; ++r) {
                v2f dx = px[r] - ax, dy = py[r] - ay, dz = pz[r] - az;
                v2f d = dx * dx + dy * dy + dz * dz;
                v2f sd = ls2 * d;
                v2f e2 = {fexp2(sd.x), fexp2(sd.y)};
                acc[r] += e2 * aw;
            }
        }
    }
#pragma unroll
    for (int r = 0; r < RPW; ++r) {
        float s = wave_reduce(acc[r].x + acc[r].y);
        if (lane == 0) {
            float rv = mR_b[col0 + r];
            float sumr = rv * s;
            float cons = fminf(rv / (sumr + EMD_EPS), 1.0f);
            rr_b[col0 + r] = cons * rv;
            mR_b[col0 + r] = fmaxf(0.0f, rv - sumr);
        }
    }
}

// ---------------------------------------------------------------- phase: row pass t (+pass1 t+1)
template <bool SQ>
__device__ __forceinline__ void phase_row(
        const float* __restrict__ x1, const float* __restrict__ x2,
        float* __restrict__ rl_b, const float* __restrict__ rr_b,
        float* __restrict__ mL_b, const float* __restrict__ mR_b,
        float* __restrict__ S_L,
        float4* sA, float4* sB, float2* sC,
        int b, int row0, int lane, int tid, float ls2, float ls2n,
        float& wcost, bool addSL) {
    const float2* x2x = (const float2*)(x2);
    const float2* x2y = (const float2*)(x2 + NPTS);
    const float2* x2z = (const float2*)(x2 + 2 * NPTS);
    const float2* wRv = (const float2*)(rr_b);
    const float2* w2v = (const float2*)(mR_b);
    float px[RPW], py[RPW], pz[RPW];
    v2f acc_a[RPW], acc_c[RPW], acc_s[RPW];
#pragma unroll
    for (int r = 0; r < RPW; ++r) {
        px[r] = x1[row0 + r];
        py[r] = x1[NPTS + row0 + r];
        pz[r] = x1[2 * NPTS + row0 + r];
        acc_a[r] = (v2f)(0.0f);
        acc_c[r] = (v2f)(0.0f);
        acc_s[r] = (v2f)(0.0f);
    }
    for (int c0 = 0; c0 < NPTS; c0 += TILE) {
        __syncthreads();
        {
            int e = c0 / 2 + tid;
            float2 xx = x2x[e], yy = x2y[e], zz = x2z[e], wr = wRv[e];
            sA[tid] = make_float4(xx.x, xx.y, yy.x, yy.y);
            sB[tid] = make_float4(zz.x, zz.y, wr.x, wr.y);
            sC[tid] = w2v[e];
        }
        __syncthreads();
#pragma unroll 2
        for (int j = 0; j < TILE / 128; ++j) {
            float4 a = sA[lane + 64 * j];
            float4 bq = sB[lane + 64 * j];
            float2 c = sC[lane + 64 * j];
            v2f ax = {a.x, a.y}, ay = {a.z, a.w};
            v2f az = {bq.x, bq.y}, wr = {bq.z, bq.w};
            v2f cw = {c.x, c.y};
#pragma unroll
            for (int r = 0; r < RPW; ++r) {
                v2f dx = px[r] - ax, dy = py[r] - ay, dz = pz[r] - az;
                v2f d = dx * dx + dy * dy + dz * dz;
                v2f er;
                if (SQ) {
                    v2f sd = ls2n * d;
                    v2f e2 = {fexp2(sd.x), fexp2(sd.y)};
                    acc_s[r] += e2 * cw;
                    v2f e4 = e2 * e2;
                    er = (e4 * e4) * wr;
                } else {
                    v2f sd = ls2 * d;
                    v2f e1 = {fexp2(sd.x), fexp2(sd.y)};
                    er = e1 * wr;
                    acc_s[r] += cw;   // e2 == 1 when next level == 0
                }
                acc_a[r] += er;
                v2f sq = {fsqrt(d.x), fsqrt(d.y)};
                acc_c[r] += er * sq;
            }
        }
    }
#pragma unroll
    for (int r = 0; r < RPW; ++r) {
        float sa = wave_reduce(acc_a[r].x + acc_a[r].y);
        float sc = wave_reduce(acc_c[r].x + acc_c[r].y);
        float ss = wave_reduce(acc_s[r].x + acc_s[r].y);
        if (lane == 0) {
            float rl = rl_b[row0 + r];
            float rem = fmaxf(0.0f, mL_b[row0 + r] - rl * sa);
            mL_b[row0 + r] = rem;
            float nrl = rem / (EMD_EPS + ss);   // next sweep's ratioL
            rl_b[row0 + r] = nrl;
            if (addSL) atomicAdd(&S_L[b], nrl);
            wcost = fmaf(rl, sc, wcost);
        }
    }
}

// ---------------------------------------------------------------- phase: level-0 cost
__device__ __forceinline__ void phase_cost_l0(
        const float* __restrict__ x1, const float* __restrict__ x2,
        const float* __restrict__ rl_b, const float* __restrict__ mR_b,
        const float* __restrict__ S_L,
        float4* sA, float4* sB, int b, int row0, int lane, int tid,
        float& wcost) {
    const float sL = S_L[b];
    const float2* x2x = (const float2*)(x2);
    const float2* x2y = (const float2*)(x2 + NPTS);
    const float2* x2z = (const float2*)(x2 + 2 * NPTS);
    const float2* wRv = (const float2*)(mR_b);
    float px[RPW], py[RPW], pz[RPW];
    v2f acc_c[RPW];
#pragma unroll
    for (int r = 0; r < RPW; ++r) {
        px[r] = x1[row0 + r];
        py[r] = x1[NPTS + row0 + r];
        pz[r] = x1[2 * NPTS + row0 + r];
        acc_c[r] = (v2f)(0.0f);
    }
    for (int c0 = 0; c0 < NPTS; c0 += TILE) {
        __syncthreads();
        {
            int e = c0 / 2 + tid;
            float2 xx = x2x[e], yy = x2y[e], zz = x2z[e], rv = wRv[e];
            float wr0 = fminf(rv.x / (rv.x * sL + EMD_EPS), 1.0f) * rv.x;
            float wr1 = fminf(rv.y / (rv.y * sL + EMD_EPS), 1.0f) * rv.y;
            sA[tid] = make_float4(xx.x, xx.y, yy.x, yy.y);
            sB[tid] = make_float4(zz.x, zz.y, wr0, wr1);
        }
        __syncthreads();
#pragma unroll 2
        for (int j = 0; j < TILE / 128; ++j) {
            float4 a = sA[lane + 64 * j];
            float4 bq = sB[lane + 64 * j];
            v2f ax = {a.x, a.y}, ay = {a.z, a.w};
            v2f az = {bq.x, bq.y}, wr = {bq.z, bq.w};
#pragma unroll
            for (int r = 0; r < RPW; ++r) {
                v2f dx = px[r] - ax, dy = py[r] - ay, dz = pz[r] - az;
                v2f d = dx * dx + dy * dy + dz * dz;
                v2f sq = {fsqrt(d.x), fsqrt(d.y)};
                acc_c[r] += wr * sq;
            }
        }
    }
#pragma unroll
    for (int r = 0; r < RPW; ++r) {
        float sc = wave_reduce(acc_c[r].x + acc_c[r].y);
        if (lane == 0) wcost = fmaf(rl_b[row0 + r], sc, wcost);
    }
}

// ---------------------------------------------------------------- mega kernel
__global__ __launch_bounds__(THREADS, 8) void k_mega(
        const float* __restrict__ xyz1, const float* __restrict__ xyz2,
        float* __restrict__ remainL, float* __restrict__ remainR,
        float* __restrict__ ratioL, float* __restrict__ ratioR,
        unsigned* __restrict__ bar, float* __restrict__ S_L,
        float* __restrict__ cost_total, float* __restrict__ out) {
    const int tid = threadIdx.x;
    const int wave = tid >> 6, lane = tid & 63;
    const int wi = blockIdx.x;            // 0..2047
    const int b = wi >> 9;                // 512 blocks per batch
    const int rb = wi & 511;
    const int row0 = rb * RPB + wave * RPW;

    const float* x1 = xyz1 + b * 3 * NPTS;
    const float* x2 = xyz2 + b * 3 * NPTS;
    float* rl_b = ratioL + b * NPTS;
    float* rr_b = ratioR + b * NPTS;
    float* mL_b = remainL + b * NPTS;
    float* mR_b = remainR + b * NPTS;

    __shared__ float smem[2564];          // 10.3 KB
    float4* sA = (float4*)smem;           // 256 float4
    float4* sB = (float4*)(smem + 1024);  // 256 float4
    float2* sC = (float2*)(smem + 2048);  // 256 float2
    float*  s_cost = smem + 2560;         // 4

    int bk = 0;
    const float LOG2E = 1.4426950408889634f;
    float lv = -16384.0f;                 // level -(4^7), scaled by exact 0.25x

    // ---- sweep-0 row pass (remainR == 1); also inits remainL/remainR
    phase_rowL0(x1, x2, rl_b, mL_b, mR_b, sA, sC, row0, lane, tid, lv * LOG2E);
    grid_barrier(bar, bk++);

    float wcost = 0.0f;
    for (int t = 0; t < 9; ++t) {
        float ls2 = lv * LOG2E;
        phase_col(x1, x2, rl_b, rr_b, mR_b, sA, sB, row0, lane, tid, ls2);
        grid_barrier(bar, bk++);
        if (t < 8) {
            float ls2n = 0.25f * ls2;     // exact; next level is 4x smaller
            phase_row<true>(x1, x2, rl_b, rr_b, mL_b, mR_b, S_L, sA, sB, sC,
                            b, row0, lane, tid, ls2, ls2n, wcost, false);
        } else {
            phase_row<false>(x1, x2, rl_b, rr_b, mL_b, mR_b, S_L, sA, sB, sC,
                             b, row0, lane, tid, ls2, 0.0f, wcost, true);
        }
        grid_barrier(bar, bk++);
        lv *= 0.25f;
    }

    // ---- sweep 9 (level == 0) cost pass; ratioR inline from remainR & S_L
    phase_cost_l0(x1, x2, rl_b, mR_b, S_L, sA, sB, b, row0, lane, tid, wcost);

    if (lane == 0) s_cost[wave] = wcost;
    __syncthreads();
    if (tid == 0)
        atomicAdd(cost_total, s_cost[0] + s_cost[1] + s_cost[2] + s_cost[3]);
    grid_barrier(bar, bk++);
    if (wi == 0 && tid == 0)
        out[0] = cost_total[0] / ((float)NPTS * (float)BATCH);
}

extern "C" void kernel_launch(void* const* d_in, const int* in_sizes, int n_in,
                              void* d_out, int out_size, void* d_ws, size_t ws_size,
                              hipStream_t stream) {
    const float* xyz1 = (const float*)d_in[0];
    const float* xyz2 = (const float*)d_in[1];
    float* out = (float*)d_out;

    const int BN = BATCH * NPTS;
    // layout: [0, 4KB): barrier slots (20 x {cnt,flag} on separate 64B lines)
    //         [4KB, 8KB): S_L[4], cost_total[1]  (zeroed with barrier area)
    //         [8KB, ...): remainL/remainR/ratioL/ratioR (BN floats each)
    unsigned* bar = (unsigned*)d_ws;
    float* misc = (float*)d_ws + 1024;
    float* S_L = misc;                    // 4
    float* cost_total = misc + 4;         // 1
    float* arrs = (float*)d_ws + 2048;
    float* remainL = arrs;
    float* remainR = arrs + 1 * BN;
    float* ratioL  = arrs + 2 * BN;
    float* ratioR  = arrs + 3 * BN;

    hipMemsetAsync(d_ws, 0, 8192, stream);   // zero barriers + S_L + cost
    k_mega<<<dim3(GRID_BLKS), dim3(THREADS), 0, stream>>>(
        xyz1, xyz2, remainL, remainR, ratioL, ratioR, bar, S_L, cost_total, out);
}

// Round 10
// 700.487 us; speedup vs baseline: 14.8339x; 14.8339x over previous
//
#include <hip/hip_runtime.h>

// approxmatch EMD (Fan et al.) on MI355X, B=4, N=M=4096, layout (B,3,N).
// Round 10: R6 multi-kernel structure (proven 533us) + x-coordinate sort and
// wave-uniform x-window culling. R5's Morton bbox failed (octant corners all
// touch the origin); a 1-D x-sort gives disjoint tile intervals. Culling is
// bit-exact: skip only where |ls2|*d2 >= 168 -> exp2 == +0.0f (2^-168 under-
// flows past denormals); cost_fused middle band (168..672) computes acc_s
// only (er = e2^4 provably 0). Mega-kernel path abandoned (R7/R8/R9: launch
// failure / 8-wave latency collapse / VGPR-64 spill).
// Math: packed v2f (v_pk_*), exp-chaining e_t = (e_{t+1})^4, pass3(t)+
// pass1(t+1) fused, level-0 specialcased; S_L folded into t=8 cost_fused.

#define NPTS 4096
#define BATCH 4
#define EMD_EPS 1e-9f
#define TILE 1024        // columns staged per LDS stage
#define RPW 2            // rows per wave, in registers
#define THREADS 256      // 4 waves
#define RPB 8            // rows per block = 4 waves * RPW
#define NBLK (NPTS / RPB)  // 512 row-blocks per batch
#define NTILE 32         // 128-col x-interval tiles per batch side

typedef float v2f __attribute__((ext_vector_type(2)));

__device__ __forceinline__ float fexp2(float x) {
#if __has_builtin(__builtin_amdgcn_exp2f)
    return __builtin_amdgcn_exp2f(x);
#else
    return exp2f(x);
#endif
}
__device__ __forceinline__ float fsqrt(float x) {
#if __has_builtin(__builtin_amdgcn_sqrtf)
    return __builtin_amdgcn_sqrtf(x);
#else
    return __sqrtf(x);
#endif
}

__device__ __forceinline__ float wave_reduce(float v) {
    v += __shfl_xor(v, 32);
    v += __shfl_xor(v, 16);
    v += __shfl_xor(v, 8);
    v += __shfl_xor(v, 4);
    v += __shfl_xor(v, 2);
    v += __shfl_xor(v, 1);
    return v;
}

// ---------------------------------------------------------------- x-sort
// counting sort by 12-bit quantized x (monotone key); one 1024-thread block
// per (side, batch). Sort machinery validated in R5 (passed absmax 0).
__global__ __launch_bounds__(1024) void k_sortx(
        const float* __restrict__ xyz1, const float* __restrict__ xyz2,
        float* __restrict__ x1s, float* __restrict__ x2s) {
    const int side = blockIdx.x, b = blockIdx.y;
    const float* src = (side ? xyz2 : xyz1) + b * 3 * NPTS;
    float* dst = (side ? x2s : x1s) + b * 3 * NPTS;
    const int tid = threadIdx.x;
    const int lane = tid & 63, wave = tid >> 6;

    __shared__ unsigned hist[4096];
    __shared__ unsigned short keys[4096];
    __shared__ unsigned warr[16];

    for (int i = tid; i < 4096; i += 1024) hist[i] = 0u;
    __syncthreads();
    for (int i = tid; i < NPTS; i += 1024) {
        float x = src[i];
        int k = (int)((x + 6.0f) * 341.0f);
        k = min(max(k, 0), 4095);
        keys[i] = (unsigned short)k;
        atomicAdd(&hist[k], 1u);
    }
    __syncthreads();
    const int base = tid * 4;
    unsigned h0 = hist[base], h1 = hist[base + 1], h2 = hist[base + 2], h3 = hist[base + 3];
    unsigned st = h0 + h1 + h2 + h3;
    unsigned v = st;
    for (int d = 1; d < 64; d <<= 1) {
        unsigned u = __shfl_up(v, d);
        if (lane >= d) v += u;
    }
    if (lane == 63) warr[wave] = v;
    __syncthreads();
    if (tid == 0) {
        unsigned run = 0;
        for (int w = 0; w < 16; ++w) { unsigned t = warr[w]; warr[w] = run; run += t; }
    }
    __syncthreads();
    unsigned off = warr[wave] + (v - st);
    hist[base] = off;
    hist[base + 1] = off + h0;
    hist[base + 2] = off + h0 + h1;
    hist[base + 3] = off + h0 + h1 + h2;
    __syncthreads();
    for (int i = tid; i < NPTS; i += 1024) {
        unsigned k = keys[i];
        unsigned pos = atomicAdd(&hist[k], 1u);
        dst[pos] = src[i];
        dst[NPTS + pos] = src[NPTS + i];
        dst[2 * NPTS + pos] = src[2 * NPTS + i];
    }
}

// per-128-point-tile x min/max; grid (NTILE, BATCH, 2), 64 threads
__global__ void k_xbounds(const float* __restrict__ x1s, const float* __restrict__ x2s,
                          float* __restrict__ bx1, float* __restrict__ bx2) {
    const int tile = blockIdx.x, b = blockIdx.y, side = blockIdx.z;
    const float* src = (side ? x2s : x1s) + b * 3 * NPTS + tile * 128;
    float* o = (side ? bx2 : bx1) + (b * NTILE + tile) * 2;
    const int lane = threadIdx.x;
    float mn = 1e30f, mx = -1e30f;
    for (int i = lane; i < 128; i += 64) {
        float x = src[i];
        mn = fminf(mn, x); mx = fmaxf(mx, x);
    }
    for (int d = 32; d; d >>= 1) {
        mn = fminf(mn, __shfl_xor(mn, d));
        mx = fmaxf(mx, __shfl_xor(mx, d));
    }
    if (lane == 0) { o[0] = mn; o[1] = mx; }
}

// wave-uniform x-interval mindist^2 vs tile ti
#define XMD2(ti)                                                             \
    float bmn = sBB[(ti) * 2], bmx = sBB[(ti) * 2 + 1];                      \
    float dd = fmaxf(0.0f, fmaxf(bmn - gmx, gmn - bmx));                     \
    float md2 = dd * dd;

// ---------------------------------------------------------------- pass 1 (sweep 0 only)
// remainR == 1 -> ratioL = 1/(eps + sum exp2(ls2*d)); inits remainL/remainR,
// zeroes S_L.
__global__ __launch_bounds__(THREADS, 6) void k_ratioL0(
        const float* __restrict__ x1s, const float* __restrict__ x2s,
        const float* __restrict__ bx2,
        float* __restrict__ ratioL, float* __restrict__ remainL,
        float* __restrict__ remainR, float* __restrict__ S_L,
        float ls2, float thr) {
    const int b = blockIdx.y;
    const int tid = threadIdx.x;
    const int wave = tid >> 6;
    const int lane = tid & 63;
    const int row0 = blockIdx.x * RPB + wave * RPW;

    if (blockIdx.x == 0 && tid == 0) S_L[b] = 0.0f;

    const float* x1 = x1s + b * 3 * NPTS;
    const float* x2 = x2s + b * 3 * NPTS;
    const float2* x2x = (const float2*)(x2);
    const float2* x2y = (const float2*)(x2 + NPTS);
    const float2* x2z = (const float2*)(x2 + 2 * NPTS);

    float px[RPW], py[RPW], pz[RPW];
    v2f acc[RPW];
#pragma unroll
    for (int r = 0; r < RPW; ++r) {
        px[r] = x1[row0 + r];
        py[r] = x1[NPTS + row0 + r];
        pz[r] = x1[2 * NPTS + row0 + r];
        acc[r] = (v2f)(0.0f);
    }
    const float gmn = fminf(px[0], px[1]), gmx = fmaxf(px[0], px[1]);

    __shared__ float4 sA[TILE / 2];   // x0,x1,y0,y1
    __shared__ float2 sZ[TILE / 2];   // z0,z1
    __shared__ float sBB[NTILE * 2];
    if (tid < NTILE * 2) sBB[tid] = bx2[b * NTILE * 2 + tid];

    for (int c0 = 0; c0 < NPTS; c0 += TILE) {
        __syncthreads();
        for (int i = tid; i < TILE / 2; i += THREADS) {
            int e = c0 / 2 + i;
            float2 xx = x2x[e], yy = x2y[e];
            sA[i] = make_float4(xx.x, xx.y, yy.x, yy.y);
            sZ[i] = x2z[e];
        }
        __syncthreads();
#pragma unroll 2
        for (int j = 0; j < TILE / 128; ++j) {
            XMD2((c0 >> 7) + j);
            if (md2 < thr) {
                float4 a = sA[lane + 64 * j];
                float2 z = sZ[lane + 64 * j];
                v2f ax = {a.x, a.y}, ay = {a.z, a.w}, az = {z.x, z.y};
#pragma unroll
                for (int r = 0; r < RPW; ++r) {
                    v2f dx = px[r] - ax, dy = py[r] - ay, dz = pz[r] - az;
                    v2f d = dx * dx + dy * dy + dz * dz;
                    v2f sd = ls2 * d;
                    v2f e2 = {fexp2(sd.x), fexp2(sd.y)};
                    acc[r] += e2;
                }
            }
        }
    }
#pragma unroll
    for (int r = 0; r < RPW; ++r) {
        float s = wave_reduce(acc[r].x + acc[r].y);
        if (lane == 0) {
            int idx = b * NPTS + row0 + r;
            ratioL[idx] = 1.0f / (EMD_EPS + s);
            remainL[idx] = 1.0f;
            remainR[idx] = 1.0f;
        }
    }
}

// ---------------------------------------------------------------- pass 2
__global__ __launch_bounds__(THREADS, 6) void k_ratioR(
        const float* __restrict__ x1s, const float* __restrict__ x2s,
        const float* __restrict__ bx1,
        const float* __restrict__ ratioL, float* __restrict__ ratioR,
        float* __restrict__ remainR, float ls2, float thr) {
    const int b = blockIdx.y;
    const int tid = threadIdx.x;
    const int wave = tid >> 6;
    const int lane = tid & 63;
    const int col0 = blockIdx.x * RPB + wave * RPW;

    const float* x1 = x1s + b * 3 * NPTS;
    const float* x2 = x2s + b * 3 * NPTS;
    const float2* x1x = (const float2*)(x1);
    const float2* x1y = (const float2*)(x1 + NPTS);
    const float2* x1z = (const float2*)(x1 + 2 * NPTS);
    const float2* wLv = (const float2*)(ratioL + b * NPTS);

    float px[RPW], py[RPW], pz[RPW];
    v2f acc[RPW];
#pragma unroll
    for (int r = 0; r < RPW; ++r) {
        px[r] = x2[col0 + r];
        py[r] = x2[NPTS + col0 + r];
        pz[r] = x2[2 * NPTS + col0 + r];
        acc[r] = (v2f)(0.0f);
    }
    const float gmn = fminf(px[0], px[1]), gmx = fmaxf(px[0], px[1]);

    __shared__ float4 sA[TILE / 2];   // x0,x1,y0,y1
    __shared__ float4 sB[TILE / 2];   // z0,z1,w0,w1
    __shared__ float sBB[NTILE * 2];
    if (tid < NTILE * 2) sBB[tid] = bx1[b * NTILE * 2 + tid];

    for (int c0 = 0; c0 < NPTS; c0 += TILE) {
        __syncthreads();
        for (int i = tid; i < TILE / 2; i += THREADS) {
            int e = c0 / 2 + i;
            float2 xx = x1x[e], yy = x1y[e], zz = x1z[e], ww = wLv[e];
            sA[i] = make_float4(xx.x, xx.y, yy.x, yy.y);
            sB[i] = make_float4(zz.x, zz.y, ww.x, ww.y);
        }
        __syncthreads();
#pragma unroll 2
        for (int j = 0; j < TILE / 128; ++j) {
            XMD2((c0 >> 7) + j);
            if (md2 < thr) {
                float4 a = sA[lane + 64 * j];
                float4 bq = sB[lane + 64 * j];
                v2f ax = {a.x, a.y}, ay = {a.z, a.w};
                v2f az = {bq.x, bq.y}, aw = {bq.z, bq.w};
#pragma unroll
                for (int r = 0; r < RPW; ++r) {
                    v2f dx = px[r] - ax, dy = py[r] - ay, dz = pz[r] - az;
                    v2f d = dx * dx + dy * dy + dz * dz;
                    v2f sd = ls2 * d;
                    v2f e2 = {fexp2(sd.x), fexp2(sd.y)};
                    acc[r] += e2 * aw;
                }
            }
        }
    }
#pragma unroll
    for (int r = 0; r < RPW; ++r) {
        float s = wave_reduce(acc[r].x + acc[r].y);
        if (lane == 0) {
            int idx = b * NPTS + col0 + r;
            float rv = remainR[idx];
            float sumr = rv * s;
            float cons = fminf(rv / (sumr + EMD_EPS), 1.0f);
            ratioR[idx] = cons * rv;
            remainR[idx] = fmaxf(0.0f, rv - sumr);
        }
    }
}

// ---------------------------------------------------------------- pass 3(t) + pass 1(t+1) fused
// SQ: e2 = exp2(ls2n*d); er = e2^4*ratioR (ls2 == 4*ls2n exactly).
// !SQ (t=8): er = exp2(ls2*d)*ratioR, e2 == 1; thrF=thrT=INF (dense) + S_L.
// Windows: md2 >= thrF (=168/|ls2n|) -> all terms exactly 0, skip.
//          md2 >= thrT (=168/|ls2|)  -> er = e2^4 underflows to 0 exactly;
//                                       compute acc_s only (no sqrt/e4).
template <bool SQ>
__global__ __launch_bounds__(THREADS, 6) void k_cost_fused(
        const float* __restrict__ x1s, const float* __restrict__ x2s,
        const float* __restrict__ bx2,
        float* __restrict__ ratioL, const float* __restrict__ ratioR,
        float* __restrict__ remainL, const float* __restrict__ remainR,
        float* __restrict__ S_L, float* __restrict__ cost_part,
        float ls2, float ls2n, float thrF, float thrT,
        int initCost, int addSL) {
    const int b = blockIdx.y;
    const int tid = threadIdx.x;
    const int wave = tid >> 6;
    const int lane = tid & 63;
    const int row0 = blockIdx.x * RPB + wave * RPW;

    const float* x1 = x1s + b * 3 * NPTS;
    const float* x2 = x2s + b * 3 * NPTS;
    const float2* x2x = (const float2*)(x2);
    const float2* x2y = (const float2*)(x2 + NPTS);
    const float2* x2z = (const float2*)(x2 + 2 * NPTS);
    const float2* wRv = (const float2*)(ratioR + b * NPTS);
    const float2* w2v = (const float2*)(remainR + b * NPTS);

    float px[RPW], py[RPW], pz[RPW];
    v2f acc_a[RPW], acc_c[RPW], acc_s[RPW];
#pragma unroll
    for (int r = 0; r < RPW; ++r) {
        px[r] = x1[row0 + r];
        py[r] = x1[NPTS + row0 + r];
        pz[r] = x1[2 * NPTS + row0 + r];
        acc_a[r] = (v2f)(0.0f);
        acc_c[r] = (v2f)(0.0f);
        acc_s[r] = (v2f)(0.0f);
    }
    const float gmn = fminf(px[0], px[1]), gmx = fmaxf(px[0], px[1]);

    __shared__ float4 sA[TILE / 2];   // x0,x1,y0,y1
    __shared__ float4 sB[TILE / 2];   // z0,z1,wR0,wR1
    __shared__ float2 sC[TILE / 2];   // w20,w21
    __shared__ float sBB[NTILE * 2];
    __shared__ float s_cost[THREADS / 64];
    if (tid < NTILE * 2) sBB[tid] = bx2[b * NTILE * 2 + tid];

    for (int c0 = 0; c0 < NPTS; c0 += TILE) {
        __syncthreads();
        for (int i = tid; i < TILE / 2; i += THREADS) {
            int e = c0 / 2 + i;
            float2 xx = x2x[e], yy = x2y[e], zz = x2z[e], wr = wRv[e];
            sA[i] = make_float4(xx.x, xx.y, yy.x, yy.y);
            sB[i] = make_float4(zz.x, zz.y, wr.x, wr.y);
            sC[i] = w2v[e];
        }
        __syncthreads();
#pragma unroll 2
        for (int j = 0; j < TILE / 128; ++j) {
            XMD2((c0 >> 7) + j);
            if (md2 < thrF) {
                float4 a = sA[lane + 64 * j];
                float4 bq = sB[lane + 64 * j];
                float2 c = sC[lane + 64 * j];
                v2f ax = {a.x, a.y}, ay = {a.z, a.w};
                v2f az = {bq.x, bq.y}, wr = {bq.z, bq.w};
                v2f cw = {c.x, c.y};
                if (SQ && md2 >= thrT) {
                    // er provably underflows to 0: acc_s only
#pragma unroll
                    for (int r = 0; r < RPW; ++r) {
                        v2f dx = px[r] - ax, dy = py[r] - ay, dz = pz[r] - az;
                        v2f d = dx * dx + dy * dy + dz * dz;
                        v2f sd = ls2n * d;
                        v2f e2 = {fexp2(sd.x), fexp2(sd.y)};
                        acc_s[r] += e2 * cw;
                    }
                } else {
#pragma unroll
                    for (int r = 0; r < RPW; ++r) {
                        v2f dx = px[r] - ax, dy = py[r] - ay, dz = pz[r] - az;
                        v2f d = dx * dx + dy * dy + dz * dz;
                        v2f er;
                        if (SQ) {
                            v2f sd = ls2n * d;
                            v2f e2 = {fexp2(sd.x), fexp2(sd.y)};
                            acc_s[r] += e2 * cw;
                            v2f e4 = e2 * e2;
                            er = (e4 * e4) * wr;
                        } else {
                            v2f sd = ls2 * d;
                            v2f e1 = {fexp2(sd.x), fexp2(sd.y)};
                            er = e1 * wr;
                            acc_s[r] += cw;   // e2 == 1 when next level == 0
                        }
                        acc_a[r] += er;
                        v2f sq = {fsqrt(d.x), fsqrt(d.y)};
                        acc_c[r] += er * sq;
                    }
                }
            }
        }
    }
    float wcost = 0.0f;
#pragma unroll
    for (int r = 0; r < RPW; ++r) {
        float sa = wave_reduce(acc_a[r].x + acc_a[r].y);
        float sc = wave_reduce(acc_c[r].x + acc_c[r].y);
        float ss = wave_reduce(acc_s[r].x + acc_s[r].y);
        if (lane == 0) {
            int idx = b * NPTS + row0 + r;
            float rl = ratioL[idx];
            float rem = fmaxf(0.0f, remainL[idx] - rl * sa);
            remainL[idx] = rem;
            float nrl = rem / (EMD_EPS + ss);   // next sweep's ratioL
            ratioL[idx] = nrl;
            if (addSL) atomicAdd(&S_L[b], nrl);
            wcost = fmaf(rl, sc, wcost);
        }
    }
    if (lane == 0) s_cost[wave] = wcost;
    __syncthreads();
    if (tid == 0) {
        float t = s_cost[0] + s_cost[1] + s_cost[2] + s_cost[3];
        int ci = b * NBLK + blockIdx.x;
        cost_part[ci] = (initCost ? t : cost_part[ci] + t);
    }
}

// ---------------------------------------------------------------- level-0 cost (dense)
__global__ __launch_bounds__(THREADS, 6) void k_cost_l0(
        const float* __restrict__ x1s, const float* __restrict__ x2s,
        const float* __restrict__ ratioL, const float* __restrict__ remainR,
        const float* __restrict__ S_L, float* __restrict__ cost_part) {
    const int b = blockIdx.y;
    const int tid = threadIdx.x;
    const int wave = tid >> 6;
    const int lane = tid & 63;
    const int row0 = blockIdx.x * RPB + wave * RPW;
    const float sL = S_L[b];

    const float* x1 = x1s + b * 3 * NPTS;
    const float* x2 = x2s + b * 3 * NPTS;
    const float2* x2x = (const float2*)(x2);
    const float2* x2y = (const float2*)(x2 + NPTS);
    const float2* x2z = (const float2*)(x2 + 2 * NPTS);
    const float2* wRv = (const float2*)(remainR + b * NPTS);

    float px[RPW], py[RPW], pz[RPW];
    v2f acc_c[RPW];
#pragma unroll
    for (int r = 0; r < RPW; ++r) {
        px[r] = x1[row0 + r];
        py[r] = x1[NPTS + row0 + r];
        pz[r] = x1[2 * NPTS + row0 + r];
        acc_c[r] = (v2f)(0.0f);
    }
    __shared__ float4 sA[TILE / 2];
    __shared__ float4 sB[TILE / 2];
    __shared__ float s_cost[THREADS / 64];

    for (int c0 = 0; c0 < NPTS; c0 += TILE) {
        __syncthreads();
        for (int i = tid; i < TILE / 2; i += THREADS) {
            int e = c0 / 2 + i;
            float2 xx = x2x[e], yy = x2y[e], zz = x2z[e], rv = wRv[e];
            float wr0 = fminf(rv.x / (rv.x * sL + EMD_EPS), 1.0f) * rv.x;
            float wr1 = fminf(rv.y / (rv.y * sL + EMD_EPS), 1.0f) * rv.y;
            sA[i] = make_float4(xx.x, xx.y, yy.x, yy.y);
            sB[i] = make_float4(zz.x, zz.y, wr0, wr1);
        }
        __syncthreads();
#pragma unroll 2
        for (int j = 0; j < TILE / 128; ++j) {
            float4 a = sA[lane + 64 * j];
            float4 bq = sB[lane + 64 * j];
            v2f ax = {a.x, a.y}, ay = {a.z, a.w};
            v2f az = {bq.x, bq.y}, wr = {bq.z, bq.w};
#pragma unroll
            for (int r = 0; r < RPW; ++r) {
                v2f dx = px[r] - ax, dy = py[r] - ay, dz = pz[r] - az;
                v2f d = dx * dx + dy * dy + dz * dz;
                v2f sq = {fsqrt(d.x), fsqrt(d.y)};
                acc_c[r] += wr * sq;
            }
        }
    }
    float wcost = 0.0f;
#pragma unroll
    for (int r = 0; r < RPW; ++r) {
        float sc = wave_reduce(acc_c[r].x + acc_c[r].y);
        if (lane == 0)
            wcost = fmaf(ratioL[b * NPTS + row0 + r], sc, wcost);
    }
    if (lane == 0) s_cost[wave] = wcost;
    __syncthreads();
    if (tid == 0) {
        float t = s_cost[0] + s_cost[1] + s_cost[2] + s_cost[3];
        cost_part[b * NBLK + blockIdx.x] += t;
    }
}

// ---------------------------------------------------------------- finalize
__global__ void k_final(const float* __restrict__ cost_part, float* __restrict__ out) {
    const int tid = threadIdx.x;
    float s = 0.0f;
    for (int i = tid; i < BATCH * NBLK; i += 256) s += cost_part[i];
    s = wave_reduce(s);
    __shared__ float sw[4];
    if ((tid & 63) == 0) sw[tid >> 6] = s;
    __syncthreads();
    if (tid == 0) out[0] = (sw[0] + sw[1] + sw[2] + sw[3]) / ((float)NPTS * (float)BATCH);
}

extern "C" void kernel_launch(void* const* d_in, const int* in_sizes, int n_in,
                              void* d_out, int out_size, void* d_ws, size_t ws_size,
                              hipStream_t stream) {
    const float* xyz1 = (const float*)d_in[0];
    const float* xyz2 = (const float*)d_in[1];
    float* out = (float*)d_out;

    const int BN = BATCH * NPTS;
    float* ws = (float*)d_ws;
    float* remainL   = ws;                       // BN
    float* remainR   = ws + 1 * BN;              // BN
    float* ratioL    = ws + 2 * BN;              // BN
    float* ratioR    = ws + 3 * BN;              // BN
    float* cost_part = ws + 4 * BN;              // BATCH*NBLK = 2048
    float* S_L       = cost_part + BATCH * NBLK; // 4
    float* x1s       = S_L + 4;                  // 3*BN (8B-aligned offset)
    float* x2s       = x1s + 3 * BN;             // 3*BN
    float* bx1       = x2s + 3 * BN;             // BATCH*NTILE*2
    float* bx2       = bx1 + BATCH * NTILE * 2;

    // levels: -(4^j) for j = 7..-1, then 0; premultiplied by log2(e).
    // ls2[t] == 4*ls2[t+1] exactly (power-of-4 levels).
    static const float levels[10] = {
        -16384.0f, -4096.0f, -1024.0f, -256.0f, -64.0f,
        -16.0f, -4.0f, -1.0f, -0.25f, 0.0f};
    float ls2[10], thrR[10];
    for (int t = 0; t < 10; ++t) {
        ls2[t] = (float)(levels[t] * 1.4426950408889634);
        thrR[t] = (t < 9) ? (168.0f / -ls2[t]) : 3.0e38f;
    }
    const float INF_THR = 3.0e38f;

    dim3 grid(NBLK, BATCH);

    k_sortx<<<dim3(2, BATCH), 1024, 0, stream>>>(xyz1, xyz2, x1s, x2s);
    k_xbounds<<<dim3(NTILE, BATCH, 2), 64, 0, stream>>>(x1s, x2s, bx1, bx2);

    k_ratioL0<<<grid, THREADS, 0, stream>>>(x1s, x2s, bx2, ratioL, remainL, remainR,
                                            S_L, ls2[0], thrR[0]);
    for (int t = 0; t < 8; ++t) {
        // cost_fused windows: full-skip at 168/|ls2n| = 4*thrR[t];
        // acc_s-only (er underflows) beyond thrR[t].
        k_ratioR<<<grid, THREADS, 0, stream>>>(x1s, x2s, bx1, ratioL, ratioR, remainR,
                                               ls2[t], thrR[t]);
        k_cost_fused<true><<<grid, THREADS, 0, stream>>>(
            x1s, x2s, bx2, ratioL, ratioR, remainL, remainR, S_L, cost_part,
            ls2[t], ls2[t + 1], 4.0f * thrR[t], thrR[t], t == 0 ? 1 : 0, 0);
    }
    // t = 8: next level is 0 -> direct-exp dense variant; fold S_L accumulation
    k_ratioR<<<grid, THREADS, 0, stream>>>(x1s, x2s, bx1, ratioL, ratioR, remainR,
                                           ls2[8], thrR[8]);
    k_cost_fused<false><<<grid, THREADS, 0, stream>>>(
        x1s, x2s, bx2, ratioL, ratioR, remainL, remainR, S_L, cost_part,
        ls2[8], 0.0f, INF_THR, INF_THR, 0, 1);
    // sweep 9 (level == 0): ratioR inline in cost_l0 from remainR & S_L
    k_cost_l0<<<grid, THREADS, 0, stream>>>(x1s, x2s, ratioL, remainR, S_L, cost_part);
    k_final<<<1, 256, 0, stream>>>(cost_part, out);
}